// Round 13
// baseline (469.246 us; speedup 1.0000x reference)
//
#include <hip/hip_runtime.h>
#include <hip/hip_fp16.h>

typedef __attribute__((ext_vector_type(8))) short short8;
typedef __attribute__((ext_vector_type(4))) float f32x4;
typedef unsigned short ushort_t;
typedef unsigned int uint_t;

#define B_SZ 32
#define T_SZ 4096
#define D_IN 256
#define H_SZ 256
#define M_SZ (B_SZ * T_SZ)  // 131072
#define CHUNK 64
#define NCHUNK (T_SZ / CHUNK)  // 64

__device__ __forceinline__ ushort_t f2bf(float f) {
  unsigned int u = __float_as_uint(f);
  unsigned int r = (u + 0x7FFFu + ((u >> 16) & 1u)) >> 16;
  return (ushort_t)r;
}

__device__ __forceinline__ float sigmoidf_(float xv) {
  float e = __expf(-fabsf(xv));
  float s = 1.0f / (1.0f + e);
  return xv >= 0.0f ? s : 1.0f - s;
}

__device__ __forceinline__ float unpack_lo(uint_t pk) {
  return __half2float(__ushort_as_half((ushort_t)(pk & 0xFFFFu)));
}
__device__ __forceinline__ float unpack_hi(uint_t pk) {
  return __half2float(__ushort_as_half((ushort_t)(pk >> 16)));
}

// ---------------------------------------------------------------------------
// Kernel 1 (unchanged): pack W'' (Wz,Wh interleaved by 16-col groups) into
// bf16, GRANULE-MAJOR per kstep: source granule g = ks*2048 + c*512 + n.
// W''[n] -> gate = (n>>4)&1 (0=Wz,1=Wh), h = (n>>5)*16 + (n&15).
// ---------------------------------------------------------------------------
__global__ void prep_w(const float* __restrict__ Wz, const float* __restrict__ Wh,
                       ushort_t* __restrict__ wsB) {
  int g = blockIdx.x * 256 + threadIdx.x;  // 16384 granules total
  if (g >= 8 * 2048) return;
  int ks = g >> 11;
  int r = g & 2047;
  int c = r >> 9;        // 0..3
  int n = r & 511;       // 0..511
  int h = (n >> 5) * 16 + (n & 15);
  const float* W = ((n >> 4) & 1) ? Wh : Wz;
  const float* src = W + (size_t)h * D_IN + ks * 32 + c * 8;
  ushort_t* dst = wsB + (size_t)g * 8;
#pragma unroll
  for (int j = 0; j < 8; ++j) dst[j] = f2bf(src[j]);
}

// ---------------------------------------------------------------------------
// Kernel 2: wave-occupancy GEMM. BM=128 x BN=256, BK=32, 8 ksteps.
// 512 threads = 8 waves in 2(M) x 4(N); wave tile 64x64, acc[4][4].
// LDS = A 2x8KB + B 2x16KB = 48KB -> 3 blocks/CU = 24 waves/CU (6/SIMD),
// vs 16 in all prior rounds — the first variant that raises wave count.
// Grid = 1024 row-blocks x 2 n-halves (x re-read per n-half is L3-cheap, r12).
// A: thread t stages granule t = c*128+row (row=t&127, c=t>>7): T14 pattern.
// B: global_load_lds width=16; 2 calls/wave: g2=(wid*2+cc)*64+lane,
//    src granule = ks*2048 + (g2>>8)*512 + n0 + (g2&255), dst = g2.
// Epilogue: gate math + packed av + fused chunk-affine reduce (r9 pattern);
// hh = (bid&1)*128 + (wc*2+i)*16 + col16; chunkIdx = (bid>>1)*2 + wr.
// ---------------------------------------------------------------------------
__global__ __launch_bounds__(512, 6) void gemm_av(
    const float* __restrict__ x, const ushort_t* __restrict__ wsB,
    const float* __restrict__ bz, const float* __restrict__ bh,
    uint_t* __restrict__ av, float2* cAV) {
  __shared__ __align__(16) unsigned char lds[49152];
  ushort_t* As = (ushort_t*)lds;                  // 2 x 8192 B  (4096 el/buf)
  ushort_t* Bs = (ushort_t*)(lds + 16384);        // 2 x 16384 B (8192 el/buf)

  const int tid = threadIdx.x;
  const int lane = tid & 63;
  const int wid = tid >> 6;         // 0..7
  const int wr = wid >> 2;          // 0..1 (M half)
  const int wc = wid & 3;           // 0..3 (N group)
  const int bid = blockIdx.x;
  const int m0 = (bid >> 1) * 128;
  const int n0 = (bid & 1) * 256;   // interleaved-col base

  // A-stage: thread t owns granule t = c*128 + row (row = t&127, c = t>>7).
  const int a_row = tid & 127;
  const int a_c = tid >> 7;
  const float* asrc = x + (size_t)(m0 + a_row) * D_IN + a_c * 8;

  // B staging: 2 calls per wave, 1KB each.
  auto STAGE_B = [&](int ks, int buf) {
#pragma unroll
    for (int cc = 0; cc < 2; ++cc) {
      const int idx2 = wid * 2 + cc;       // 0..15
      const int cb = idx2 >> 2;            // k-chunk 0..3
      const int nnb = (idx2 & 3) * 64;     // nn base
      const ushort_t* bsrc =
          wsB + ((size_t)ks * 2048 + cb * 512 + n0 + nnb + lane) * 8;
      ushort_t* bdst = Bs + buf * 8192 + (idx2 * 64 + lane) * 8;
      __builtin_amdgcn_global_load_lds(
          (const __attribute__((address_space(1))) void*)bsrc,
          (__attribute__((address_space(3))) void*)bdst, 16, 0, 0);
    }
  };

  f32x4 acc[4][4];
#pragma unroll
  for (int rt = 0; rt < 4; ++rt)
#pragma unroll
    for (int ct = 0; ct < 4; ++ct) {
      f32x4 z4 = {0.f, 0.f, 0.f, 0.f};
      acc[rt][ct] = z4;
    }

  // ---- prologue: stage kstep 0 into buffer 0 ----
  STAGE_B(0, 0);
  {
    float4 f0 = *(const float4*)(asrc);
    float4 f1 = *(const float4*)(asrc + 4);
    union { ushort_t e[8]; short8 s; } cv;
    cv.e[0] = f2bf(f0.x); cv.e[1] = f2bf(f0.y);
    cv.e[2] = f2bf(f0.z); cv.e[3] = f2bf(f0.w);
    cv.e[4] = f2bf(f1.x); cv.e[5] = f2bf(f1.y);
    cv.e[6] = f2bf(f1.z); cv.e[7] = f2bf(f1.w);
    *(short8*)(As + tid * 8) = cv.s;  // granule == tid
  }
  __syncthreads();

#pragma unroll
  for (int ks = 0; ks < 8; ++ks) {
    const int cur = ks & 1;
    // 1. LDS -> register fragments
    short8 afr[4], bfr[4];
    {
      const int c = lane >> 4;
      const int r16 = lane & 15;
#pragma unroll
      for (int rt = 0; rt < 4; ++rt) {
        int row = wr * 64 + rt * 16 + r16;
        afr[rt] = *(const short8*)(As + cur * 4096 + (c * 128 + row) * 8);
      }
#pragma unroll
      for (int ct = 0; ct < 4; ++ct) {
        int nn = wc * 64 + ct * 16 + r16;
        bfr[ct] = *(const short8*)(Bs + cur * 8192 + (c * 256 + nn) * 8);
      }
    }
    // 2. issue next-kstep staging (latency hides under MFMAs)
    float4 nf0, nf1;
    if (ks < 7) {
      STAGE_B(ks + 1, cur ^ 1);
      nf0 = *(const float4*)(asrc + (ks + 1) * 32);
      nf1 = *(const float4*)(asrc + (ks + 1) * 32 + 4);
    }
    // 3. MFMAs
#pragma unroll
    for (int rt = 0; rt < 4; ++rt)
#pragma unroll
      for (int ct = 0; ct < 4; ++ct)
        acc[rt][ct] = __builtin_amdgcn_mfma_f32_16x16x32_bf16(
            afr[rt], bfr[ct], acc[rt][ct], 0, 0, 0);
    // 4. A write-late (reg->LDS after compute)
    if (ks < 7) {
      union { ushort_t e[8]; short8 s; } cv;
      cv.e[0] = f2bf(nf0.x); cv.e[1] = f2bf(nf0.y);
      cv.e[2] = f2bf(nf0.z); cv.e[3] = f2bf(nf0.w);
      cv.e[4] = f2bf(nf1.x); cv.e[5] = f2bf(nf1.y);
      cv.e[6] = f2bf(nf1.z); cv.e[7] = f2bf(nf1.w);
      *(short8*)(As + (cur ^ 1) * 4096 + tid * 8) = cv.s;
    }
    __syncthreads();
  }

  // ---- epilogue: gate math + av + fused chunk-affine reduce ----
  const int col16 = lane & 15;
  const int rgrp = lane >> 4;
#pragma unroll
  for (int i = 0; i < 2; ++i) {
    int hh = (bid & 1) * 128 + (wc * 2 + i) * 16 + col16;
    float bzv = bz[hh];
    float bhv = bh[hh];
    float CA = 1.0f, CV = 0.0f;   // running compose over rt windows
#pragma unroll
    for (int rt = 0; rt < 4; ++rt) {
      float A4 = 1.0f, V4 = 0.0f; // this thread's 4 rows (ascending j = time)
#pragma unroll
      for (int j = 0; j < 4; ++j) {
        int row = m0 + wr * 64 + rt * 16 + rgrp * 4 + j;
        float kv = acc[rt][2 * i][j] + bzv;
        float pv = acc[rt][2 * i + 1][j] + bhv;
        float a = sigmoidf_(-kv);       // 1 - sigmoid(k)
        float z = 1.0f - a;             // sigmoid(k)
        float gg = (pv >= 0.0f) ? (pv + 0.5f) : sigmoidf_(pv);
        float vv = z * gg;
        uint_t pk = (uint_t)__half_as_ushort(__float2half_rn(a)) |
                    ((uint_t)__half_as_ushort(__float2half_rn(vv)) << 16);
        av[(size_t)row * H_SZ + hh] = pk;
        V4 = fmaf(a, V4, vv);
        A4 *= a;
      }
      // butterfly compose across rgrp (time order)
      float Ap = __shfl_xor(A4, 16);
      float Vp = __shfl_xor(V4, 16);
      float A8 = A4 * Ap;
      float V8 = (lane & 16) ? fmaf(A4, Vp, V4) : fmaf(Ap, V4, Vp);
      float Ap2 = __shfl_xor(A8, 32);
      float Vp2 = __shfl_xor(V8, 32);
      float A16 = A8 * Ap2;
      float V16 = (lane & 32) ? fmaf(A8, Vp2, V8) : fmaf(Ap2, V8, Vp2);
      // rt windows ascend in time
      CV = fmaf(A16, CV, V16);
      CA = CA * A16;
    }
    if (cAV != nullptr && lane < 16) {
      float2 r; r.x = CA; r.y = CV;
      // chunkIdx = (bid>>1)*2 + wr  (BM=128 spans two 64-row chunks)
      cAV[(size_t)((bid >> 1) * 2 + wr) * H_SZ + hh] = r;
    }
  }
}

// ---------------------------------------------------------------------------
// Phase 2 (unchanged): per (b,h) sequentially compose chunk summaries from
// g(h0), writing the INCOMING h for each chunk. 32 blocks x 256 thr.
// ---------------------------------------------------------------------------
__global__ __launch_bounds__(256) void chunk_carry(
    const float* __restrict__ h0, const float2* __restrict__ cAV,
    float* __restrict__ hb) {
  const int b = blockIdx.x;
  const int h = threadIdx.x;
  float v0 = h0[b * H_SZ + h];
  float hc = (v0 >= 0.0f) ? (v0 + 0.5f) : sigmoidf_(v0);

  const float2* p = cAV + (size_t)b * NCHUNK * H_SZ + h;
  float* o = hb + (size_t)b * NCHUNK * H_SZ + h;

  float2 buf[NCHUNK];
#pragma unroll
  for (int c = 0; c < NCHUNK; ++c) buf[c] = p[(size_t)c * H_SZ];

#pragma unroll
  for (int c = 0; c < NCHUNK; ++c) {
    o[(size_t)c * H_SZ] = hc;
    hc = fmaf(buf[c].x, hc, buf[c].y);
  }
}

// ---------------------------------------------------------------------------
// Phase 3 (unchanged): per (b, chunk): start from carry, re-scan av, write
// fp32 out. av may alias out (in-place fallback).
// ---------------------------------------------------------------------------
__global__ __launch_bounds__(256) void chunk_scan_out(
    const uint_t* av, const float* __restrict__ hb, float* out) {
  const int b = blockIdx.x >> 6;
  const int c = blockIdx.x & 63;
  const int h = threadIdx.x;

  float hc = hb[((size_t)b * NCHUNK + c) * H_SZ + h];
  const uint_t* p = av + ((size_t)b * T_SZ + c * CHUNK) * H_SZ + h;
  float* o = out + ((size_t)b * T_SZ + c * CHUNK) * H_SZ + h;

  uint_t buf[CHUNK];
#pragma unroll
  for (int s = 0; s < CHUNK; ++s) buf[s] = p[(size_t)s * H_SZ];

#pragma unroll
  for (int s = 0; s < CHUNK; ++s) {
    float a = unpack_lo(buf[s]);
    float v = unpack_hi(buf[s]);
    hc = fmaf(a, hc, v);
    o[(size_t)s * H_SZ] = hc;
  }
}

// Fallback (unchanged): fully-sequential scan.
__global__ __launch_bounds__(64) void scan_seq(const float* __restrict__ h0,
                                               const uint_t* av, float* out) {
  const int b = blockIdx.x >> 2;
  const int hg = blockIdx.x & 3;
  const int h = hg * 64 + threadIdx.x;

  float v0 = h0[b * H_SZ + h];
  float hc = (v0 >= 0.0f) ? (v0 + 0.5f) : sigmoidf_(v0);

  const uint_t* p = av + (size_t)b * T_SZ * H_SZ + h;
  float* o = out + (size_t)b * T_SZ * H_SZ + h;

  uint_t buf[32];
#pragma unroll
  for (int d = 0; d < 32; ++d) buf[d] = p[(size_t)d * H_SZ];

  for (int t0 = 0; t0 < T_SZ; t0 += 32) {
#pragma unroll
    for (int d = 0; d < 32; ++d) {
      int t = t0 + d;
      uint_t pk = buf[d];
      int tn = t + 32;
      if (tn < T_SZ) buf[d] = p[(size_t)tn * H_SZ];
      hc = fmaf(unpack_lo(pk), hc, unpack_hi(pk));
      o[(size_t)t * H_SZ] = hc;
    }
  }
}

extern "C" void kernel_launch(void* const* d_in, const int* in_sizes, int n_in,
                              void* d_out, int out_size, void* d_ws, size_t ws_size,
                              hipStream_t stream) {
  const float* x  = (const float*)d_in[0];
  const float* h0 = (const float*)d_in[1];
  const float* Wz = (const float*)d_in[2];
  const float* bz = (const float*)d_in[3];
  const float* Wh = (const float*)d_in[4];
  const float* bh = (const float*)d_in[5];
  float* out = (float*)d_out;

  // ws layout: [wsB 256K][cAV 4M][hb 2M][pad to 8M][av 134M if it fits]
  const size_t wsBBytes = 262144;
  const size_t cavBytes = (size_t)B_SZ * NCHUNK * H_SZ * 8;   // 4 MiB
  const size_t hbBytes  = (size_t)B_SZ * NCHUNK * H_SZ * 4;   // 2 MiB
  const size_t avOff    = 8388608;
  const size_t avBytes  = (size_t)M_SZ * H_SZ * 4;            // 134 MiB

  ushort_t* wsB = (ushort_t*)d_ws;
  float2* cAV = (float2*)((char*)d_ws + wsBBytes);
  float* hb   = (float*)((char*)d_ws + wsBBytes + cavBytes);

  const bool haveSummaries = ws_size >= wsBBytes + cavBytes + hbBytes;
  uint_t* av;
  if (ws_size >= avOff + avBytes) {
    av = (uint_t*)((char*)d_ws + avOff);
  } else {
    av = (uint_t*)d_out;  // in-place: scan reads av[t] before writing h[t]
  }

  prep_w<<<64, 256, 0, stream>>>(Wz, Wh, wsB);
  gemm_av<<<(M_SZ / 128) * 2, 512, 0, stream>>>(x, wsB, bz, bh, av,
                                                haveSummaries ? cAV : (float2*)nullptr);
  if (haveSummaries) {
    chunk_carry<<<B_SZ, 256, 0, stream>>>(h0, cAV, hb);
    chunk_scan_out<<<B_SZ * NCHUNK, 256, 0, stream>>>(av, hb, out);
  } else {
    scan_seq<<<B_SZ * 4, 64, 0, stream>>>(h0, av, out);
  }
}

// Round 14
// 166.843 us; speedup vs baseline: 2.8125x; 2.8125x over previous
//
#include <hip/hip_runtime.h>
#include <hip/hip_fp16.h>

typedef __attribute__((ext_vector_type(8))) short short8;
typedef __attribute__((ext_vector_type(4))) float f32x4;
typedef unsigned short ushort_t;
typedef unsigned int uint_t;

#define B_SZ 32
#define T_SZ 4096
#define D_IN 256
#define H_SZ 256
#define M_SZ (B_SZ * T_SZ)  // 131072
#define CHUNK 64
#define NCHUNK (T_SZ / CHUNK)  // 64

__device__ __forceinline__ ushort_t f2bf(float f) {
  unsigned int u = __float_as_uint(f);
  unsigned int r = (u + 0x7FFFu + ((u >> 16) & 1u)) >> 16;
  return (ushort_t)r;
}

__device__ __forceinline__ float sigmoidf_(float xv) {
  float e = __expf(-fabsf(xv));
  float s = 1.0f / (1.0f + e);
  return xv >= 0.0f ? s : 1.0f - s;
}

__device__ __forceinline__ float unpack_lo(uint_t pk) {
  return __half2float(__ushort_as_half((ushort_t)(pk & 0xFFFFu)));
}
__device__ __forceinline__ float unpack_hi(uint_t pk) {
  return __half2float(__ushort_as_half((ushort_t)(pk >> 16)));
}

// ---------------------------------------------------------------------------
// Kernel 1 (r9 verbatim): pack W'' (Wz,Wh interleaved by 16-col groups) into
// bf16, GRANULE-MAJOR per kstep: granule g = ks*2048 + c*512 + n.
// W''[n] -> gate = (n>>4)&1 (0=Wz,1=Wh), h = (n>>5)*16 + (n&15).
// ---------------------------------------------------------------------------
__global__ void prep_w(const float* __restrict__ Wz, const float* __restrict__ Wh,
                       ushort_t* __restrict__ wsB) {
  int g = blockIdx.x * 256 + threadIdx.x;  // 16384 granules total
  if (g >= 8 * 2048) return;
  int ks = g >> 11;
  int r = g & 2047;
  int c = r >> 9;        // 0..3
  int n = r & 511;       // 0..511
  int h = (n >> 5) * 16 + (n & 15);
  const float* W = ((n >> 4) & 1) ? Wh : Wz;
  const float* src = W + (size_t)h * D_IN + ks * 32 + c * 8;
  ushort_t* dst = wsB + (size_t)g * 8;
#pragma unroll
  for (int j = 0; j < 8; ++j) dst[j] = f2bf(src[j]);
}

// ---------------------------------------------------------------------------
// Kernel 2: r9 GEMM with ONE structural change — B SINGLE-buffered (32KB).
// LDS = A 2x4KB + B 1x32KB = 40KB -> 3 blocks/CU (24 waves) vs r9's 2 (16).
// Per kstep: read A/B frags -> barrier#1 (all waves done reading B(ks)) ->
// issue B(ks+1) into the SAME buffer + A loads -> MFMA (B already in regs)
// -> A cvt/ds_write -> barrier#2 (syncthreads drains stage + ds_write).
// Two barriers/kstep, but each block's drain overlaps two other resident
// blocks' compute (the axis that produced r2->r3's win). VGPR stays ~64
// (r9-identical register footprint) so 8 waves/SIMD remain feasible.
// Epilogue: r9 verbatim (gate math + packed av + fused chunk-affine reduce).
// ---------------------------------------------------------------------------
__global__ __launch_bounds__(512, 4) void gemm_av(
    const float* __restrict__ x, const ushort_t* __restrict__ wsB,
    const float* __restrict__ bz, const float* __restrict__ bh,
    uint_t* __restrict__ av, float2* cAV) {
  __shared__ __align__(16) unsigned char lds[40960];
  ushort_t* As = (ushort_t*)lds;                  // 2 x 4096 B (2048 el/buf)
  ushort_t* Bs = (ushort_t*)(lds + 8192);         // 1 x 32768 B (16384 el)

  const int tid = threadIdx.x;
  const int lane = tid & 63;
  const int wid = tid >> 6;         // 0..7 = N-group
  const int m0 = blockIdx.x * 64;

  // A-stage mapping (threads 0..255): granule G = g*64 + row, g = 16B k-chunk
  const int a_row = tid & 63;
  const int a_g = tid >> 6;         // valid for tid<256
  const float* asrc = x + (size_t)(m0 + a_row) * D_IN + a_g * 8;

  // B staging: issue kstep ks' 4 gload_lds (1KB each per wave) into Bs
  auto STAGE_B = [&](int ks) {
    const ushort_t* bsrc = wsB + (size_t)ks * 16384 + wid * 2048 + lane * 8;
    ushort_t* bdst = Bs + wid * 2048;
#pragma unroll
    for (int cc = 0; cc < 4; ++cc) {
      __builtin_amdgcn_global_load_lds(
          (const __attribute__((address_space(1))) void*)(bsrc + cc * 512),
          (__attribute__((address_space(3))) void*)(bdst + cc * 512), 16, 0, 0);
    }
  };

  f32x4 acc[4][4];
#pragma unroll
  for (int rt = 0; rt < 4; ++rt)
#pragma unroll
    for (int ct = 0; ct < 4; ++ct) {
      f32x4 z4 = {0.f, 0.f, 0.f, 0.f};
      acc[rt][ct] = z4;
    }

  // ---- prologue: stage kstep 0 (B into single buffer, A into buf 0) ----
  STAGE_B(0);
  if (tid < 256) {
    float4 f0 = *(const float4*)(asrc);
    float4 f1 = *(const float4*)(asrc + 4);
    union { ushort_t e[8]; short8 s; } cv;
    cv.e[0] = f2bf(f0.x); cv.e[1] = f2bf(f0.y);
    cv.e[2] = f2bf(f0.z); cv.e[3] = f2bf(f0.w);
    cv.e[4] = f2bf(f1.x); cv.e[5] = f2bf(f1.y);
    cv.e[6] = f2bf(f1.z); cv.e[7] = f2bf(f1.w);
    *(short8*)(As + tid * 8) = cv.s;
  }
  __syncthreads();

#pragma unroll
  for (int ks = 0; ks < 8; ++ks) {
    const int cur = ks & 1;
    // 1. LDS -> register fragments (granule-major: granule = c*NROWS + idx)
    short8 afr[4], bfr[4];
    {
      const int c = lane >> 4;
      const int r16 = lane & 15;
#pragma unroll
      for (int rt = 0; rt < 4; ++rt) {
        int row = rt * 16 + r16;
        afr[rt] = *(const short8*)(As + cur * 2048 + (c * 64 + row) * 8);
      }
#pragma unroll
      for (int ct = 0; ct < 4; ++ct) {
        int n = wid * 64 + ct * 16 + r16;
        bfr[ct] = *(const short8*)(Bs + (c * 512 + n) * 8);
      }
    }
    if (ks < 7) {
      // barrier#1: every wave has finished reading B(ks) from LDS;
      // safe to overwrite the single B buffer with B(ks+1).
      __syncthreads();
      STAGE_B(ks + 1);
    }
    // 2. A loads for next kstep (T14 issue-early)
    float4 nf0, nf1;
    if (ks < 7 && tid < 256) {
      nf0 = *(const float4*)(asrc + (ks + 1) * 32);
      nf1 = *(const float4*)(asrc + (ks + 1) * 32 + 4);
    }
    // 3. MFMAs (B operands already in registers)
#pragma unroll
    for (int rt = 0; rt < 4; ++rt)
#pragma unroll
      for (int ct = 0; ct < 4; ++ct)
        acc[rt][ct] = __builtin_amdgcn_mfma_f32_16x16x32_bf16(
            afr[rt], bfr[ct], acc[rt][ct], 0, 0, 0);
    // 4. A write-late (reg->LDS after compute)
    if (ks < 7 && tid < 256) {
      union { ushort_t e[8]; short8 s; } cv;
      cv.e[0] = f2bf(nf0.x); cv.e[1] = f2bf(nf0.y);
      cv.e[2] = f2bf(nf0.z); cv.e[3] = f2bf(nf0.w);
      cv.e[4] = f2bf(nf1.x); cv.e[5] = f2bf(nf1.y);
      cv.e[6] = f2bf(nf1.z); cv.e[7] = f2bf(nf1.w);
      *(short8*)(As + (cur ^ 1) * 2048 + tid * 8) = cv.s;
    }
    // barrier#2: drains B(ks+1) gload_lds and A ds_write before next reads.
    if (ks < 7) __syncthreads();
  }

  // ---- epilogue (r9 verbatim): gate math + av + fused chunk-affine reduce ----
  const int col16 = lane & 15;
  const int rgrp = lane >> 4;
#pragma unroll
  for (int i = 0; i < 2; ++i) {
    int hh = (wid * 2 + i) * 16 + col16;
    float bzv = bz[hh];
    float bhv = bh[hh];
    float CA = 1.0f, CV = 0.0f;   // running compose over rt windows
#pragma unroll
    for (int rt = 0; rt < 4; ++rt) {
      float A4 = 1.0f, V4 = 0.0f; // this thread's 4 rows (ascending j = time)
#pragma unroll
      for (int j = 0; j < 4; ++j) {
        int row = m0 + rt * 16 + rgrp * 4 + j;
        float kv = acc[rt][2 * i][j] + bzv;
        float pv = acc[rt][2 * i + 1][j] + bhv;
        float a = sigmoidf_(-kv);       // 1 - sigmoid(k)
        float z = 1.0f - a;             // sigmoid(k)
        float gg = (pv >= 0.0f) ? (pv + 0.5f) : sigmoidf_(pv);
        float vv = z * gg;
        uint_t pk = (uint_t)__half_as_ushort(__float2half_rn(a)) |
                    ((uint_t)__half_as_ushort(__float2half_rn(vv)) << 16);
        av[(size_t)row * H_SZ + hh] = pk;
        V4 = fmaf(a, V4, vv);
        A4 *= a;
      }
      // butterfly compose across rgrp (time order)
      float Ap = __shfl_xor(A4, 16);
      float Vp = __shfl_xor(V4, 16);
      float A8 = A4 * Ap;
      float V8 = (lane & 16) ? fmaf(A4, Vp, V4) : fmaf(Ap, V4, Vp);
      float Ap2 = __shfl_xor(A8, 32);
      float Vp2 = __shfl_xor(V8, 32);
      float A16 = A8 * Ap2;
      float V16 = (lane & 32) ? fmaf(A8, Vp2, V8) : fmaf(Ap2, V8, Vp2);
      // rt windows ascend in time
      CV = fmaf(A16, CV, V16);
      CA = CA * A16;
    }
    if (cAV != nullptr && lane < 16) {
      float2 r; r.x = CA; r.y = CV;
      cAV[(size_t)blockIdx.x * H_SZ + hh] = r;  // chunkIdx == blockIdx.x
    }
  }
}

// ---------------------------------------------------------------------------
// Phase 2 (unchanged): per (b,h) sequentially compose chunk summaries from
// g(h0), writing the INCOMING h for each chunk. 32 blocks x 256 thr.
// ---------------------------------------------------------------------------
__global__ __launch_bounds__(256) void chunk_carry(
    const float* __restrict__ h0, const float2* __restrict__ cAV,
    float* __restrict__ hb) {
  const int b = blockIdx.x;
  const int h = threadIdx.x;
  float v0 = h0[b * H_SZ + h];
  float hc = (v0 >= 0.0f) ? (v0 + 0.5f) : sigmoidf_(v0);

  const float2* p = cAV + (size_t)b * NCHUNK * H_SZ + h;
  float* o = hb + (size_t)b * NCHUNK * H_SZ + h;

  float2 buf[NCHUNK];
#pragma unroll
  for (int c = 0; c < NCHUNK; ++c) buf[c] = p[(size_t)c * H_SZ];

#pragma unroll
  for (int c = 0; c < NCHUNK; ++c) {
    o[(size_t)c * H_SZ] = hc;
    hc = fmaf(buf[c].x, hc, buf[c].y);
  }
}

// ---------------------------------------------------------------------------
// Phase 3 (unchanged): per (b, chunk): start from carry, re-scan av, write
// fp32 out. av may alias out (in-place fallback): per-thread loads strictly
// precede stores; no __restrict__ on av/out.
// ---------------------------------------------------------------------------
__global__ __launch_bounds__(256) void chunk_scan_out(
    const uint_t* av, const float* __restrict__ hb, float* out) {
  const int b = blockIdx.x >> 6;
  const int c = blockIdx.x & 63;
  const int h = threadIdx.x;

  float hc = hb[((size_t)b * NCHUNK + c) * H_SZ + h];
  const uint_t* p = av + ((size_t)b * T_SZ + c * CHUNK) * H_SZ + h;
  float* o = out + ((size_t)b * T_SZ + c * CHUNK) * H_SZ + h;

  uint_t buf[CHUNK];
#pragma unroll
  for (int s = 0; s < CHUNK; ++s) buf[s] = p[(size_t)s * H_SZ];

#pragma unroll
  for (int s = 0; s < CHUNK; ++s) {
    float a = unpack_lo(buf[s]);
    float v = unpack_hi(buf[s]);
    hc = fmaf(a, hc, v);
    o[(size_t)s * H_SZ] = hc;
  }
}

// Fallback (unchanged): fully-sequential scan.
__global__ __launch_bounds__(64) void scan_seq(const float* __restrict__ h0,
                                               const uint_t* av, float* out) {
  const int b = blockIdx.x >> 2;
  const int hg = blockIdx.x & 3;
  const int h = hg * 64 + threadIdx.x;

  float v0 = h0[b * H_SZ + h];
  float hc = (v0 >= 0.0f) ? (v0 + 0.5f) : sigmoidf_(v0);

  const uint_t* p = av + (size_t)b * T_SZ * H_SZ + h;
  float* o = out + (size_t)b * T_SZ * H_SZ + h;

  uint_t buf[32];
#pragma unroll
  for (int d = 0; d < 32; ++d) buf[d] = p[(size_t)d * H_SZ];

  for (int t0 = 0; t0 < T_SZ; t0 += 32) {
#pragma unroll
    for (int d = 0; d < 32; ++d) {
      int t = t0 + d;
      uint_t pk = buf[d];
      int tn = t + 32;
      if (tn < T_SZ) buf[d] = p[(size_t)tn * H_SZ];
      hc = fmaf(unpack_lo(pk), hc, unpack_hi(pk));
      o[(size_t)t * H_SZ] = hc;
    }
  }
}

extern "C" void kernel_launch(void* const* d_in, const int* in_sizes, int n_in,
                              void* d_out, int out_size, void* d_ws, size_t ws_size,
                              hipStream_t stream) {
  const float* x  = (const float*)d_in[0];
  const float* h0 = (const float*)d_in[1];
  const float* Wz = (const float*)d_in[2];
  const float* bz = (const float*)d_in[3];
  const float* Wh = (const float*)d_in[4];
  const float* bh = (const float*)d_in[5];
  float* out = (float*)d_out;

  // ws layout: [wsB 256K][cAV 4M][hb 2M][pad to 8M][av 134M if it fits]
  const size_t wsBBytes = 262144;
  const size_t cavBytes = (size_t)B_SZ * NCHUNK * H_SZ * 8;   // 4 MiB
  const size_t hbBytes  = (size_t)B_SZ * NCHUNK * H_SZ * 4;   // 2 MiB
  const size_t avOff    = 8388608;
  const size_t avBytes  = (size_t)M_SZ * H_SZ * 4;            // 134 MiB

  ushort_t* wsB = (ushort_t*)d_ws;
  float2* cAV = (float2*)((char*)d_ws + wsBBytes);
  float* hb   = (float*)((char*)d_ws + wsBBytes + cavBytes);

  const bool haveSummaries = ws_size >= wsBBytes + cavBytes + hbBytes;
  uint_t* av;
  if (ws_size >= avOff + avBytes) {
    av = (uint_t*)((char*)d_ws + avOff);
  } else {
    av = (uint_t*)d_out;  // in-place: scan reads av[t] before writing h[t]
  }

  prep_w<<<64, 256, 0, stream>>>(Wz, Wh, wsB);
  gemm_av<<<M_SZ / 64, 512, 0, stream>>>(x, wsB, bz, bh, av,
                                         haveSummaries ? cAV : (float2*)nullptr);
  if (haveSummaries) {
    chunk_carry<<<B_SZ, 256, 0, stream>>>(h0, cAV, hb);
    chunk_scan_out<<<B_SZ * NCHUNK, 256, 0, stream>>>(av, hb, out);
  } else {
    scan_seq<<<B_SZ * 4, 64, 0, stream>>>(h0, av, out);
  }
}